// Round 1
// baseline (44.815 us; speedup 1.0000x reference)
//
#include <hip/hip_runtime.h>

// PathExplosion: per-element independent trajectory simulation.
// bound[i] = sigmoid(relu(x[i]@w1 + b1)@w2 + b2)   (scalar per row)
// per element e=(i,j):  while (xc <= 10) { xc += 0.01;
//                          if (xc <= bound) xc *= (xc <= bound-0.001) ? 2 : 3;
//                          c += 1; }
// All arithmetic in strict f32 to replay the reference's FP trajectory.

__global__ __launch_bounds__(256) void path_explosion_kernel(
    const float* __restrict__ x,   // (B,2)
    const float* __restrict__ w1,  // (2,64) row-major
    const float* __restrict__ b1,  // (64,)
    const float* __restrict__ w2,  // (64,1) -> flat 64
    const float* __restrict__ b2,  // (1,)
    float* __restrict__ out,       // (B,2) counts
    int nelem)                     // B*2
{
    int e = blockIdx.x * blockDim.x + threadIdx.x;
    if (e >= nelem) return;
    int row = e >> 1;

    float x0 = x[row * 2 + 0];
    float x1 = x[row * 2 + 1];

    // bound = sigmoid(relu(x@w1 + b1) @ w2 + b2), all f32.
    float z = 0.0f;
#pragma unroll
    for (int j = 0; j < 64; ++j) {
        // Eigen-gebp-style: acc = fma(x1, w1[1][j], round(x0*w1[0][j]))
        float t = fmaf(x1, w1[64 + j], x0 * w1[j]);
        t += b1[j];                 // matmul result rounded, then +b1 (matches ref)
        t = fmaxf(t, 0.0f);         // relu
        z = fmaf(t, w2[j], z);      // 64-length dot, sequential fmaf chain
    }
    z += b2[0];
    float bnd = 1.0f / (1.0f + __builtin_expf(-z));
    float bm  = bnd - 0.001f;       // ref computes bound - 0.001 in f32

    float xc = x[e];
    float c  = 0.0f;
    // Exact replay of the reference body. Once xc > bnd it can never re-enter
    // (xc is monotone increasing, bnd fixed), so the compare stays cheap/false.
    while (xc <= 10.0f) {
        xc += 0.01f;
        if (xc <= bnd) {
            xc *= (xc <= bm) ? 2.0f : 3.0f;
        }
        c += 1.0f;
    }
    out[e] = c;
}

extern "C" void kernel_launch(void* const* d_in, const int* in_sizes, int n_in,
                              void* d_out, int out_size, void* d_ws, size_t ws_size,
                              hipStream_t stream) {
    const float* x  = (const float*)d_in[0];
    const float* w1 = (const float*)d_in[1];
    const float* b1 = (const float*)d_in[2];
    const float* w2 = (const float*)d_in[3];
    const float* b2 = (const float*)d_in[4];
    float* out = (float*)d_out;

    int nelem = out_size;                       // B*2 = 131072
    int block = 256;
    int grid  = (nelem + block - 1) / block;    // 512 blocks
    hipLaunchKernelGGL(path_explosion_kernel, dim3(grid), dim3(block), 0, stream,
                       x, w1, b1, w2, b2, out, nelem);
}

// Round 2
// 9.622 us; speedup vs baseline: 4.6575x; 4.6575x over previous
//
#include <hip/hip_runtime.h>

// PathExplosion, analytic-tail version.
//
// Per row: bound = sigmoid(relu(x@w1+b1)@w2+b2)  (exact f32, Eigen fmaf order).
// Per element: replay the reference loop EXACTLY (f32) only while the
// multiplicative branch can fire (xc <= bnd after the +0.01 step); once
// xc > bnd it can never re-enter (bnd < 1, xc monotone increasing), and the
// remaining loop is a pure additive march:  count = floor((10 - xc)/step) + 1,
// step = (double)0.01f. Accumulated f32 rounding drift over <=1000 adds is
// <= ~5e-4 (~0.05 steps) -> at most +-1 count error, vs harness threshold 19.04.

__device__ __forceinline__ float trajectory_count(float xc, float bnd, float bm) {
    float c = 0.0f;
    // Multiplicative phase: exact f32 replay of the reference body.
    while (xc <= 10.0f) {
        xc += 0.01f;
        c += 1.0f;
        if (xc <= bnd) {
            xc *= (xc <= bm) ? 2.0f : 3.0f;   // may stay <= bnd; loop continues
        } else {
            break;                             // escaped for good (bnd < 1 < 10)
        }
    }
    // Additive tail, closed form.
    if (xc <= 10.0f) {
        const double step = (double)0.01f;     // 0.009999999776482582
        double rem = (10.0 - (double)xc) / step;
        double k = floor(rem) + 1.0;           // first k with xc + k*step > 10
        c += (float)k;
    }
    return c;
}

__global__ __launch_bounds__(256) void path_explosion_kernel(
    const float* __restrict__ x,   // (B,2)
    const float* __restrict__ w1,  // (2,64) row-major
    const float* __restrict__ b1,  // (64,)
    const float* __restrict__ w2,  // (64,)
    const float* __restrict__ b2,  // (1,)
    float* __restrict__ out,       // (B,2)
    int nrows)                     // B
{
    int row = blockIdx.x * blockDim.x + threadIdx.x;
    if (row >= nrows) return;

    float2 xr = *reinterpret_cast<const float2*>(x + row * 2);
    float x0 = xr.x, x1 = xr.y;

    // bound = sigmoid(relu(x@w1 + b1) @ w2 + b2), strict f32, Eigen fmaf order.
    float z = 0.0f;
#pragma unroll
    for (int j = 0; j < 64; ++j) {
        float t = fmaf(x1, w1[64 + j], x0 * w1[j]);  // uniform idx -> s_load
        t += b1[j];
        t = fmaxf(t, 0.0f);
        z = fmaf(t, w2[j], z);
    }
    z += b2[0];
    float bnd = 1.0f / (1.0f + __builtin_expf(-z));
    float bm  = bnd - 0.001f;

    float2 res;
    res.x = trajectory_count(x0, bnd, bm);
    res.y = trajectory_count(x1, bnd, bm);
    *reinterpret_cast<float2*>(out + row * 2) = res;
}

extern "C" void kernel_launch(void* const* d_in, const int* in_sizes, int n_in,
                              void* d_out, int out_size, void* d_ws, size_t ws_size,
                              hipStream_t stream) {
    const float* x  = (const float*)d_in[0];
    const float* w1 = (const float*)d_in[1];
    const float* b1 = (const float*)d_in[2];
    const float* w2 = (const float*)d_in[3];
    const float* b2 = (const float*)d_in[4];
    float* out = (float*)d_out;

    int nrows = out_size / 2;                   // 65536
    int block = 256;
    int grid  = (nrows + block - 1) / block;    // 256 blocks
    hipLaunchKernelGGL(path_explosion_kernel, dim3(grid), dim3(block), 0, stream,
                       x, w1, b1, w2, b2, out, nrows);
}

// Round 3
// 9.446 us; speedup vs baseline: 4.7446x; 1.0187x over previous
//
#include <hip/hip_runtime.h>

// PathExplosion, analytic-tail v2 (merged loops, f32 tail, no f64).
//
// Per row: bound = sigmoid(relu(x@w1+b1)@w2+b2)  (exact f32, Eigen fmaf order
// — this is the only numerically sensitive value; keep order fixed).
// Per element: replay the reference loop exactly (f32) during the
// multiplicative phase. During that phase xc <= 3*bnd + 0.01 < 3.01 << 10, so
// the reference's (xc <= 10) check is never false there and is dropped.
// Once xc > bnd after an increment it never re-enters (bnd < 1, xc monotone),
// leaving a pure additive march; remaining count = floor((10 - xc)/0.01f) + 1
// computed in f32 (abs error ~6e-5 steps vs ~0.05-step accepted drift).

__global__ __launch_bounds__(256) void path_explosion_kernel(
    const float* __restrict__ x,   // (B,2)
    const float* __restrict__ w1,  // (2,64) row-major
    const float* __restrict__ b1,  // (64,)
    const float* __restrict__ w2,  // (64,)
    const float* __restrict__ b2,  // (1,)
    float* __restrict__ out,       // (B,2)
    int nrows)                     // B
{
    int row = blockIdx.x * blockDim.x + threadIdx.x;
    if (row >= nrows) return;

    float2 xr = *reinterpret_cast<const float2*>(x + row * 2);
    float x0 = xr.x, x1 = xr.y;

    // bound = sigmoid(relu(x@w1 + b1) @ w2 + b2), strict f32, fixed order.
    float z = 0.0f;
#pragma unroll
    for (int j = 0; j < 64; ++j) {
        float t = fmaf(x1, w1[64 + j], x0 * w1[j]);  // uniform idx -> scalar loads
        t += b1[j];
        t = fmaxf(t, 0.0f);
        z = fmaf(t, w2[j], z);
    }
    z += b2[0];
    float bnd = 1.0f / (1.0f + __builtin_expf(-z));
    float bm  = bnd - 0.001f;

    // Multiplicative phase for both elements, interleaved (ILP 2).
    float xa = x0, xb = x1;
    float ca = 0.0f, cb = 0.0f;
    bool  da = false, db = false;
    do {
        if (!da) {
            xa += 0.01f; ca += 1.0f;
            if (xa > bnd) da = true;
            else          xa *= (xa <= bm) ? 2.0f : 3.0f;
        }
        if (!db) {
            xb += 0.01f; cb += 1.0f;
            if (xb > bnd) db = true;
            else          xb *= (xb <= bm) ? 2.0f : 3.0f;
        }
    } while (!(da && db));

    // Additive tail, closed form in f32. Post-escape xa,xb < 1.01 <= 10 always.
    const float inv_rate = 1.0f;  // divide by the literal f32 0.01f below
    (void)inv_rate;
    ca += floorf((10.0f - xa) / 0.01f) + 1.0f;
    cb += floorf((10.0f - xb) / 0.01f) + 1.0f;

    float2 res; res.x = ca; res.y = cb;
    *reinterpret_cast<float2*>(out + row * 2) = res;
}

extern "C" void kernel_launch(void* const* d_in, const int* in_sizes, int n_in,
                              void* d_out, int out_size, void* d_ws, size_t ws_size,
                              hipStream_t stream) {
    const float* x  = (const float*)d_in[0];
    const float* w1 = (const float*)d_in[1];
    const float* b1 = (const float*)d_in[2];
    const float* w2 = (const float*)d_in[3];
    const float* b2 = (const float*)d_in[4];
    float* out = (float*)d_out;

    int nrows = out_size / 2;                   // 65536
    int block = 256;
    int grid  = (nrows + block - 1) / block;    // 256 blocks
    hipLaunchKernelGGL(path_explosion_kernel, dim3(grid), dim3(block), 0, stream,
                       x, w1, b1, w2, b2, out, nrows);
}